// Round 1
// baseline (1392.881 us; speedup 1.0000x reference)
//
#include <hip/hip_runtime.h>

// Problem constants
#define A_N   512
#define E_DIM 64
#define H_DIM 128
#define GG    64          // G*G
#define K_CAT 320         // E + H + H  (emb | soc | h)
#define NB_F  32.0f
#define T_OBS 8
#define PRED  12

typedef __attribute__((ext_vector_type(8))) short bf16x8;
typedef __attribute__((ext_vector_type(4))) float f32x4;
#define MFMA16(a,b,c) __builtin_amdgcn_mfma_f32_16x16x32_bf16((a),(b),(c),0,0,0)

// workspace offsets (bytes)
#define WP_OFF   0           // 128*8192*2      = 2097152
#define WZ_OFF   2097152     // 512*320*2       = 327680
#define BZ_OFF   2424832     // 512*4           = 2048
#define MASK_OFF 2426880     // 512*4           = 2048
#define H_OFF    2428928     // 512*128*4       = 262144
#define C_OFF    2691072     // 512*128*4       = 262144
#define CUR_OFF  2953216     // 512*2*4         = 4096
#define XCAT_OFF 2957312     // 512*320*2       = 327680
#define GRID_OFF 3284992     // 512*8192*2      = 8388608
#define PART_OFF 11673600    // 16*512*128*4    = 4194304
// total ~15.9 MB

static __device__ __forceinline__ unsigned short f2bf(float x){
    union { float f; unsigned u; } v; v.f = x;
    unsigned r = v.u + 0x7fffu + ((v.u >> 16) & 1u);   // RNE
    return (unsigned short)(r >> 16);
}

// ---------------- P0: decode mask (robust to uint8 / int32 / int64 storage) ----
__global__ void mask_decode(const unsigned char* __restrict__ mraw, int* __restrict__ mout){
    __shared__ int flagA, flagB;
    int t = threadIdx.x;
    if (t == 0){ flagA = 0; flagB = 0; }
    __syncthreads();
    if (t < 512){
        unsigned char b = mraw[t];
        if (b && (t & 3))        atomicAdd(&flagA, 1);   // nonzero off 4-byte stride -> bytes
        if (b && ((t & 7) == 4)) atomicAdd(&flagB, 1);   // -> int32
    }
    __syncthreads();
    if (t < 512){
        int v;
        if (flagA)      v = mraw[t] ? 1 : 0;
        else if (flagB) v = ((const int*)mraw)[t] ? 1 : 0;
        else            v = ((const long long*)mraw)[t] ? 1 : 0;
        mout[t] = v;
    }
}

// ---------------- P1: convert weights to bf16, zero state ---------------------
__global__ void prep(const float* __restrict__ Wp, const float* __restrict__ Wih,
                     const float* __restrict__ Whh, const float* __restrict__ bih,
                     const float* __restrict__ bhh,
                     unsigned short* __restrict__ wp_bf, unsigned short* __restrict__ wz_bf,
                     float* __restrict__ bz, float* __restrict__ h, float* __restrict__ c,
                     unsigned short* __restrict__ xcat){
    const int stride = gridDim.x * blockDim.x;
    const int i0 = blockIdx.x * blockDim.x + threadIdx.x;
    for (int i = i0; i < 128*8192; i += stride) wp_bf[i] = f2bf(Wp[i]);
    for (int i = i0; i < 512*K_CAT; i += stride){
        int n = i / K_CAT, k = i - n*K_CAT;
        float w = (k < 192) ? Wih[n*192 + k] : Whh[n*128 + (k - 192)];
        wz_bf[i] = f2bf(w);
    }
    for (int i = i0; i < 512; i += stride) bz[i] = bih[i] + bhh[i];
    for (int i = i0; i < 512*H_DIM; i += stride){ h[i] = 0.f; c[i] = 0.f; }
    for (int i = i0; i < 512*K_CAT; i += stride) xcat[i] = 0;   // bf16 zero
}

// ---------------- K1: positions, embedding, grid scatter ----------------------
// mode 0: pos = obs[t] (nan->0)   mode 1: pos = mask ? obs[T-1] : 0, write cur
// mode 2: pos = cur
__global__ __launch_bounds__(128) void scatter_step(
    const float* __restrict__ obs, const float* __restrict__ W_e,
    const float* __restrict__ b_e, const int* __restrict__ mask,
    const float* __restrict__ h, float* cur,
    unsigned short* __restrict__ grid, unsigned short* __restrict__ xcat,
    int mode, int t)
{
    __shared__ float2 pos_s[A_N];
    __shared__ float  gridl[GG * H_DIM];   // 32 KB
    __shared__ short  cellj[A_N];
    __shared__ short  list[A_N];
    __shared__ int    nvalid;
    const int i = blockIdx.x, tid = threadIdx.x;

    for (int j = tid; j < A_N; j += 128){
        float px, py;
        if (mode == 2){ px = cur[j*2]; py = cur[j*2+1]; }
        else {
            int tt = (mode == 0) ? t : (T_OBS - 1);
            px = obs[tt*1024 + j*2]; py = obs[tt*1024 + j*2 + 1];
            if (isnan(px)) px = 0.f;
            if (isnan(py)) py = 0.f;
            if (mode == 1 && !mask[j]){ px = 0.f; py = 0.f; }
        }
        pos_s[j] = make_float2(px, py);
    }
    __syncthreads();
    if (mode == 1 && i == 0){
        for (int j = tid; j < A_N; j += 128){ cur[j*2] = pos_s[j].x; cur[j*2+1] = pos_s[j].y; }
    }
    const float2 pi = pos_s[i];
    const int vi = mask[i];

    for (int j = tid; j < A_N; j += 128){
        int cc = -1;
        if (vi && j != i && mask[j]){
            float rx = pos_s[j].x - pi.x, ry = pos_s[j].y - pi.y;
            if (fabsf(rx) < NB_F && fabsf(ry) < NB_F){
                int col = (int)floorf((rx + NB_F) * 0.125f);
                int row = (int)floorf((ry + NB_F) * 0.125f);
                col = min(max(col, 0), 7); row = min(max(row, 0), 7);
                cc = row*8 + col;
            }
        }
        cellj[j] = (short)cc;
    }
    for (int k = tid; k < GG*H_DIM; k += 128) gridl[k] = 0.f;
    __syncthreads();

    // deterministic ballot compaction of valid neighbors (wave 0)
    if (tid < 64){
        int base = 0;
        for (int b = 0; b < 8; ++b){
            int j = b*64 + tid;
            short cj = cellj[j];
            bool val = cj >= 0;
            unsigned long long bal = __ballot(val);
            int pre = __popcll(bal & ((1ull << tid) - 1ull));
            if (val) list[base + pre] = (short)(j | ((int)cj << 9));
            base += __popcll(bal);
        }
        if (tid == 0) nvalid = base;
    }
    __syncthreads();
    const int nv = nvalid;

    int n = 0;
    for (; n + 4 <= nv; n += 4){
        int p0 = list[n], p1 = list[n+1], p2 = list[n+2], p3 = list[n+3];
        float h0 = h[(p0 & 511)*H_DIM + tid];
        float h1 = h[(p1 & 511)*H_DIM + tid];
        float h2 = h[(p2 & 511)*H_DIM + tid];
        float h3 = h[(p3 & 511)*H_DIM + tid];
        gridl[(p0 >> 9)*H_DIM + tid] += h0;
        gridl[(p1 >> 9)*H_DIM + tid] += h1;
        gridl[(p2 >> 9)*H_DIM + tid] += h2;
        gridl[(p3 >> 9)*H_DIM + tid] += h3;
    }
    for (; n < nv; ++n){
        int p0 = list[n];
        gridl[(p0 >> 9)*H_DIM + tid] += h[(p0 & 511)*H_DIM + tid];
    }

    unsigned short* go = grid + (long long)i * (GG*H_DIM);
    for (int k = tid; k < GG*H_DIM; k += 128) go[k] = f2bf(gridl[k]);

    if (tid < E_DIM){
        float e = W_e[tid*2]*pi.x + W_e[tid*2+1]*pi.y + b_e[tid];
        xcat[i*K_CAT + tid] = f2bf(fmaxf(e, 0.f));
    }
}

// ---------------- K2: pooled GEMM, K-split partials ---------------------------
// part[s][m][n] = grid[m, s*512:(s+1)*512] @ W_p[n, s*512:(s+1)*512]^T
__global__ __launch_bounds__(256) void pool_gemm(
    const unsigned short* __restrict__ grid, const unsigned short* __restrict__ wp,
    float* __restrict__ part)
{
    const int mt = blockIdx.x & 15, s = blockIdx.x >> 4;
    const int wave = threadIdx.x >> 6, lane = threadIdx.x & 63;
    const int m0 = mt*32, n0 = wave*32;
    const int lrow = lane & 15, lk = (lane >> 4) * 8;
    f32x4 acc[2][2] = {};
    const unsigned short* ga = grid + (long long)(m0 + lrow)*8192 + s*512 + lk;
    const unsigned short* gb = wp   + (long long)(n0 + lrow)*8192 + s*512 + lk;
    #pragma unroll 4
    for (int kc = 0; kc < 16; ++kc){
        bf16x8 a0 = *(const bf16x8*)(ga + kc*32);
        bf16x8 a1 = *(const bf16x8*)(ga + 16*8192 + kc*32);
        bf16x8 b0 = *(const bf16x8*)(gb + kc*32);
        bf16x8 b1 = *(const bf16x8*)(gb + 16*8192 + kc*32);
        acc[0][0] = MFMA16(a0, b0, acc[0][0]);
        acc[0][1] = MFMA16(a0, b1, acc[0][1]);
        acc[1][0] = MFMA16(a1, b0, acc[1][0]);
        acc[1][1] = MFMA16(a1, b1, acc[1][1]);
    }
    float* po = part + ((long long)s*512 + m0)*128 + n0;
    const int crow = (lane >> 4) * 4, ccol = lane & 15;
    #pragma unroll
    for (int mi = 0; mi < 2; ++mi)
      #pragma unroll
      for (int ni = 0; ni < 2; ++ni)
        #pragma unroll
        for (int r = 0; r < 4; ++r)
          po[(mi*16 + crow + r)*128 + ni*16 + ccol] = acc[mi][ni][r];
}

// ---------------- K3: reduce soc + LSTM + (decoder) outputs -------------------
__global__ __launch_bounds__(256) void lstm_step(
    unsigned short* xcat,                         // read (emb,h) + write (h)
    const unsigned short* __restrict__ wz, const float* __restrict__ bz,
    const float* __restrict__ part, const float* __restrict__ b_p,
    const int* __restrict__ mask, float* h, float* c, float* cur,
    const float* __restrict__ W_o, const float* __restrict__ b_o,
    float* out, int dec_t)
{
    __shared__ unsigned short soc_lds[32][136];   // bf16, padded rows (272B, 16B-aligned)
    __shared__ float hrow[32][128];
    __shared__ float raw_lds[32][5];
    const int m0 = blockIdx.x * 32;
    const int tid = threadIdx.x;
    const int wave = tid >> 6, lane = tid & 63;

    // 1) reduce K-split partials -> soc (masked, +b_p) -> bf16 LDS
    for (int idx = tid; idx < 32*128; idx += 256){
        int r = idx >> 7, col = idx & 127;
        float sacc = b_p[col];
        #pragma unroll
        for (int s = 0; s < 16; ++s)
            sacc += part[((long long)s*512 + m0 + r)*128 + col];
        if (!mask[m0 + r]) sacc = 0.f;
        soc_lds[r][col] = f2bf(sacc);
    }
    __syncthreads();

    // 2) z = xcat @ W_z^T  (each wave owns 32 cols of EVERY gate -> no cross-wave)
    const int lrow = lane & 15, lk = (lane >> 4) * 8;
    f32x4 acc[2][4][2] = {};
    for (int kc = 0; kc < 10; ++kc){
        const int k0 = kc * 32;
        bf16x8 a0, a1;
        if (k0 >= 64 && k0 < 192){
            int kl = k0 - 64 + lk;
            a0 = *(const bf16x8*)(&soc_lds[lrow][kl]);
            a1 = *(const bf16x8*)(&soc_lds[16 + lrow][kl]);
        } else {
            const unsigned short* xp = xcat + (long long)(m0 + lrow)*K_CAT + k0 + lk;
            a0 = *(const bf16x8*)(xp);
            a1 = *(const bf16x8*)(xp + 16*K_CAT);
        }
        #pragma unroll
        for (int nb = 0; nb < 4; ++nb){
            #pragma unroll
            for (int ci = 0; ci < 2; ++ci){
                int nn = nb*128 + wave*32 + ci*16 + lrow;
                bf16x8 b = *(const bf16x8*)(wz + (long long)nn*K_CAT + k0 + lk);
                acc[0][nb][ci] = MFMA16(a0, b, acc[0][nb][ci]);
                acc[1][nb][ci] = MFMA16(a1, b, acc[1][nb][ci]);
            }
        }
    }

    // 3) gates -> c,h update (fp32), write h to global fp32 + xcat bf16 + LDS
    const int crow = (lane >> 4) * 4;
    #pragma unroll
    for (int mi = 0; mi < 2; ++mi){
      #pragma unroll
      for (int ci = 0; ci < 2; ++ci){
        #pragma unroll
        for (int r = 0; r < 4; ++r){
            int row = mi*16 + crow + r;
            int col = wave*32 + ci*16 + (lane & 15);
            float zi = acc[mi][0][ci][r] + bz[       col];
            float zf = acc[mi][1][ci][r] + bz[128  + col];
            float zg = acc[mi][2][ci][r] + bz[256  + col];
            float zo = acc[mi][3][ci][r] + bz[384  + col];
            float ig = 1.f / (1.f + expf(-zi));
            float fg = 1.f / (1.f + expf(-zf));
            float gg = tanhf(zg);
            float og = 1.f / (1.f + expf(-zo));
            long long gi = (long long)(m0 + row)*H_DIM + col;
            float cn = fg * c[gi] + ig * gg;
            float hn = og * tanhf(cn);
            c[gi] = cn; h[gi] = hn;
            hrow[row][col] = hn;
            xcat[(long long)(m0 + row)*K_CAT + 192 + col] = f2bf(hn);
        }
      }
    }
    if (dec_t < 0) return;
    __syncthreads();

    // 4) raw = h @ W_o^T + b_o ; outputs ; cur update
    if (tid < 160){
        int r = tid / 5, o = tid - r*5;
        float a2 = b_o[o];
        for (int k = 0; k < 128; ++k) a2 += W_o[o*128 + k] * hrow[r][k];
        raw_lds[r][o] = a2;
    }
    __syncthreads();
    if (tid < 32){
        int i = m0 + tid;
        float mu0 = raw_lds[tid][0], mu1 = raw_lds[tid][1];
        float s0 = expf(raw_lds[tid][2]) + 1e-6f;
        float s1 = expf(raw_lds[tid][3]) + 1e-6f;
        float rh = tanhf(raw_lds[tid][4]);
        float cx = cur[i*2], cy = cur[i*2+1];
        if (mask[i]){ cx += mu0; cy += mu1; }
        cur[i*2] = cx; cur[i*2+1] = cy;
        out[dec_t*1024 + i*2]             = cx;
        out[dec_t*1024 + i*2 + 1]         = cy;
        out[12288 + dec_t*1024 + i*2]     = s0;
        out[12288 + dec_t*1024 + i*2 + 1] = s1;
        out[24576 + dec_t*512 + i]        = rh;
    }
}

extern "C" void kernel_launch(void* const* d_in, const int* in_sizes, int n_in,
                              void* d_out, int out_size, void* d_ws, size_t ws_size,
                              hipStream_t stream)
{
    const float* obs  = (const float*)d_in[0];
    const unsigned char* mraw = (const unsigned char*)d_in[1];
    const float* W_e  = (const float*)d_in[2];
    const float* b_e  = (const float*)d_in[3];
    const float* W_p  = (const float*)d_in[4];
    const float* b_p  = (const float*)d_in[5];
    const float* W_ih = (const float*)d_in[6];
    const float* W_hh = (const float*)d_in[7];
    const float* b_ih = (const float*)d_in[8];
    const float* b_hh = (const float*)d_in[9];
    const float* W_o  = (const float*)d_in[10];
    const float* b_o  = (const float*)d_in[11];
    float* out = (float*)d_out;

    char* ws = (char*)d_ws;
    unsigned short* wp_bf = (unsigned short*)(ws + WP_OFF);
    unsigned short* wz_bf = (unsigned short*)(ws + WZ_OFF);
    float* bz   = (float*)(ws + BZ_OFF);
    int*   mski = (int*)  (ws + MASK_OFF);
    float* hbuf = (float*)(ws + H_OFF);
    float* cbuf = (float*)(ws + C_OFF);
    float* cur  = (float*)(ws + CUR_OFF);
    unsigned short* xcat = (unsigned short*)(ws + XCAT_OFF);
    unsigned short* grid = (unsigned short*)(ws + GRID_OFF);
    float* part = (float*)(ws + PART_OFF);

    mask_decode<<<1, 512, 0, stream>>>(mraw, mski);
    prep<<<1024, 256, 0, stream>>>(W_p, W_ih, W_hh, b_ih, b_hh,
                                   wp_bf, wz_bf, bz, hbuf, cbuf, xcat);

    for (int t = 0; t < T_OBS + PRED; ++t){
        int mode = (t < T_OBS) ? 0 : ((t == T_OBS) ? 1 : 2);
        scatter_step<<<A_N, 128, 0, stream>>>(obs, W_e, b_e, mski, hbuf, cur,
                                              grid, xcat, mode, t);
        pool_gemm<<<256, 256, 0, stream>>>(grid, wp_bf, part);
        lstm_step<<<16, 256, 0, stream>>>(xcat, wz_bf, bz, part, b_p, mski,
                                          hbuf, cbuf, cur, W_o, b_o, out,
                                          (t >= T_OBS) ? (t - T_OBS) : -1);
    }
}

// Round 2
// 984.700 us; speedup vs baseline: 1.4145x; 1.4145x over previous
//
#include <hip/hip_runtime.h>

// Problem constants
#define A_N   512
#define E_DIM 64
#define H_DIM 128
#define GG    64          // G*G
#define K_CAT 320         // E + H + H  (emb | soc | h)
#define NB_F  32.0f
#define T_OBS 8
#define PRED  12

typedef __attribute__((ext_vector_type(8))) short bf16x8;
typedef __attribute__((ext_vector_type(4))) float f32x4;
#define MFMA16(a,b,c) __builtin_amdgcn_mfma_f32_16x16x32_bf16((a),(b),(c),0,0,0)

// workspace offsets (bytes)
#define WP_OFF   0           // 128*8192*2      = 2097152
#define WZ_OFF   2097152     // 512*320*2       = 327680
#define BZ_OFF   2424832     // 512*4           = 2048
#define MASK_OFF 2426880     // 512*4           = 2048
#define H_OFF    2428928     // 512*128*4       = 262144
#define C_OFF    2691072     // 512*128*4       = 262144
#define CUR_OFF  2953216     // 512*2*4         = 4096
#define XCAT_OFF 2957312     // 512*320*2       = 327680
#define GRID_OFF 3284992     // 512*8192*2      = 8388608
#define PART_OFF 11673600    // 16*512*128*4    = 4194304

static __device__ __forceinline__ unsigned short f2bf(float x){
    union { float f; unsigned u; } v; v.f = x;
    unsigned r = v.u + 0x7fffu + ((v.u >> 16) & 1u);   // RNE
    return (unsigned short)(r >> 16);
}
static __device__ __forceinline__ float sigm_f(float x){
    return 1.f / (1.f + __expf(-x));
}
static __device__ __forceinline__ float tanh_f(float x){
    float e = __expf(-2.f * fabsf(x));
    float t = (1.f - e) / (1.f + e);
    return copysignf(t, x);
}

// ---------------- P0: decode mask (robust to uint8 / int32 / int64 storage) ----
__global__ void mask_decode(const unsigned char* __restrict__ mraw, int* __restrict__ mout){
    __shared__ int flagA, flagB;
    int t = threadIdx.x;
    if (t == 0){ flagA = 0; flagB = 0; }
    __syncthreads();
    if (t < 512){
        unsigned char b = mraw[t];
        if (b && (t & 3))        atomicAdd(&flagA, 1);
        if (b && ((t & 7) == 4)) atomicAdd(&flagB, 1);
    }
    __syncthreads();
    if (t < 512){
        int v;
        if (flagA)      v = mraw[t] ? 1 : 0;
        else if (flagB) v = ((const int*)mraw)[t] ? 1 : 0;
        else            v = ((const long long*)mraw)[t] ? 1 : 0;
        mout[t] = v;
    }
}

// ---------------- P1: convert weights to bf16, zero state ---------------------
__global__ void prep(const float* __restrict__ Wp, const float* __restrict__ Wih,
                     const float* __restrict__ Whh, const float* __restrict__ bih,
                     const float* __restrict__ bhh,
                     unsigned short* __restrict__ wp_bf, unsigned short* __restrict__ wz_bf,
                     float* __restrict__ bz, float* __restrict__ h, float* __restrict__ c,
                     unsigned short* __restrict__ xcat){
    const int stride = gridDim.x * blockDim.x;
    const int i0 = blockIdx.x * blockDim.x + threadIdx.x;
    for (int i = i0; i < 128*8192; i += stride) wp_bf[i] = f2bf(Wp[i]);
    for (int i = i0; i < 512*K_CAT; i += stride){
        int n = i / K_CAT, k = i - n*K_CAT;
        float w = (k < 192) ? Wih[n*192 + k] : Whh[n*128 + (k - 192)];
        wz_bf[i] = f2bf(w);
    }
    for (int i = i0; i < 512; i += stride) bz[i] = bih[i] + bhh[i];
    for (int i = i0; i < 512*H_DIM; i += stride){ h[i] = 0.f; c[i] = 0.f; }
    for (int i = i0; i < 512*K_CAT; i += stride) xcat[i] = 0;   // bf16 zero
}

// ---------------- K1: positions, embedding, grid scatter ----------------------
__global__ __launch_bounds__(128) void scatter_step(
    const float* __restrict__ obs, const float* __restrict__ W_e,
    const float* __restrict__ b_e, const int* __restrict__ mask,
    const float* __restrict__ h, float* cur,
    unsigned short* __restrict__ grid, unsigned short* __restrict__ xcat,
    int mode, int t)
{
    __shared__ float2 pos_s[A_N];
    __shared__ float  gridl[GG * H_DIM];   // 32 KB
    __shared__ short  cellj[A_N];
    __shared__ short  list[A_N];
    __shared__ int    nvalid;
    const int i = blockIdx.x, tid = threadIdx.x;

    for (int j = tid; j < A_N; j += 128){
        float px, py;
        if (mode == 2){ px = cur[j*2]; py = cur[j*2+1]; }
        else {
            int tt = (mode == 0) ? t : (T_OBS - 1);
            px = obs[tt*1024 + j*2]; py = obs[tt*1024 + j*2 + 1];
            if (isnan(px)) px = 0.f;
            if (isnan(py)) py = 0.f;
            if (mode == 1 && !mask[j]){ px = 0.f; py = 0.f; }
        }
        pos_s[j] = make_float2(px, py);
    }
    __syncthreads();
    if (mode == 1 && i == 0){
        for (int j = tid; j < A_N; j += 128){ cur[j*2] = pos_s[j].x; cur[j*2+1] = pos_s[j].y; }
    }
    const float2 pi = pos_s[i];
    const int vi = mask[i];

    for (int j = tid; j < A_N; j += 128){
        int cc = -1;
        if (vi && j != i && mask[j]){
            float rx = pos_s[j].x - pi.x, ry = pos_s[j].y - pi.y;
            if (fabsf(rx) < NB_F && fabsf(ry) < NB_F){
                int col = (int)floorf((rx + NB_F) * 0.125f);
                int row = (int)floorf((ry + NB_F) * 0.125f);
                col = min(max(col, 0), 7); row = min(max(row, 0), 7);
                cc = row*8 + col;
            }
        }
        cellj[j] = (short)cc;
    }
    for (int k = tid; k < GG*H_DIM; k += 128) gridl[k] = 0.f;
    __syncthreads();

    if (tid < 64){
        int base = 0;
        for (int b = 0; b < 8; ++b){
            int j = b*64 + tid;
            short cj = cellj[j];
            bool val = cj >= 0;
            unsigned long long bal = __ballot(val);
            int pre = __popcll(bal & ((1ull << tid) - 1ull));
            if (val) list[base + pre] = (short)(j | ((int)cj << 9));
            base += __popcll(bal);
        }
        if (tid == 0) nvalid = base;
    }
    __syncthreads();
    const int nv = nvalid;

    int n = 0;
    for (; n + 4 <= nv; n += 4){
        int p0 = list[n], p1 = list[n+1], p2 = list[n+2], p3 = list[n+3];
        float h0 = h[(p0 & 511)*H_DIM + tid];
        float h1 = h[(p1 & 511)*H_DIM + tid];
        float h2 = h[(p2 & 511)*H_DIM + tid];
        float h3 = h[(p3 & 511)*H_DIM + tid];
        gridl[(p0 >> 9)*H_DIM + tid] += h0;
        gridl[(p1 >> 9)*H_DIM + tid] += h1;
        gridl[(p2 >> 9)*H_DIM + tid] += h2;
        gridl[(p3 >> 9)*H_DIM + tid] += h3;
    }
    for (; n < nv; ++n){
        int p0 = list[n];
        gridl[(p0 >> 9)*H_DIM + tid] += h[(p0 & 511)*H_DIM + tid];
    }

    unsigned short* go = grid + (long long)i * (GG*H_DIM);
    for (int k = tid; k < GG*H_DIM; k += 128) go[k] = f2bf(gridl[k]);

    if (tid < E_DIM){
        float e = W_e[tid*2]*pi.x + W_e[tid*2+1]*pi.y + b_e[tid];
        xcat[i*K_CAT + tid] = f2bf(fmaxf(e, 0.f));
    }
}

// ---------------- K2: pooled GEMM, K-split partials ---------------------------
__global__ __launch_bounds__(256) void pool_gemm(
    const unsigned short* __restrict__ grid, const unsigned short* __restrict__ wp,
    float* __restrict__ part)
{
    const int mt = blockIdx.x & 15, s = blockIdx.x >> 4;
    const int wave = threadIdx.x >> 6, lane = threadIdx.x & 63;
    const int m0 = mt*32, n0 = wave*32;
    const int lrow = lane & 15, lk = (lane >> 4) * 8;
    f32x4 acc[2][2] = {};
    const unsigned short* ga = grid + (long long)(m0 + lrow)*8192 + s*512 + lk;
    const unsigned short* gb = wp   + (long long)(n0 + lrow)*8192 + s*512 + lk;
    #pragma unroll 4
    for (int kc = 0; kc < 16; ++kc){
        bf16x8 a0 = *(const bf16x8*)(ga + kc*32);
        bf16x8 a1 = *(const bf16x8*)(ga + 16*8192 + kc*32);
        bf16x8 b0 = *(const bf16x8*)(gb + kc*32);
        bf16x8 b1 = *(const bf16x8*)(gb + 16*8192 + kc*32);
        acc[0][0] = MFMA16(a0, b0, acc[0][0]);
        acc[0][1] = MFMA16(a0, b1, acc[0][1]);
        acc[1][0] = MFMA16(a1, b0, acc[1][0]);
        acc[1][1] = MFMA16(a1, b1, acc[1][1]);
    }
    float* po = part + ((long long)s*512 + m0)*128 + n0;
    const int crow = (lane >> 4) * 4, ccol = lane & 15;
    #pragma unroll
    for (int mi = 0; mi < 2; ++mi)
      #pragma unroll
      for (int ni = 0; ni < 2; ++ni)
        #pragma unroll
        for (int r = 0; r < 4; ++r)
          po[(mi*16 + crow + r)*128 + ni*16 + ccol] = acc[mi][ni][r];
}

// ---------------- K2b: reduce split-K partials -> soc (bf16) into xcat --------
__global__ __launch_bounds__(256) void soc_reduce(
    const float* __restrict__ part, const float* __restrict__ b_p,
    const int* __restrict__ mask, unsigned short* __restrict__ xcat)
{
    const int idx = blockIdx.x * 256 + threadIdx.x;   // 0..65535
    const int row = idx >> 7, col = idx & 127;
    float s = b_p[col];
    #pragma unroll
    for (int k = 0; k < 16; ++k)
        s += part[k*65536 + row*128 + col];
    if (!mask[row]) s = 0.f;
    xcat[row*K_CAT + 64 + col] = f2bf(s);
}

// ---------------- K3: LSTM gates + state update (64 blocks) -------------------
// block = (rt 0..15, ct 0..3): rows [rt*32,+32), H-cols [ct*32,+32)
// wave g (0..3) computes gate g's z-slice; combine via LDS.
__global__ __launch_bounds__(256) void lstm64(
    unsigned short* xcat, const unsigned short* __restrict__ wz,
    const float* __restrict__ bz, float* h, float* c)
{
    __shared__ float zbuf[4][32][33];
    const int rt = blockIdx.x >> 2, ct = blockIdx.x & 3;
    const int tid = threadIdx.x, g = tid >> 6, lane = tid & 63;
    const int lrow = lane & 15, lk = (lane >> 4) * 8;
    const int m0 = rt * 32;

    f32x4 acc[2][2] = {};
    const unsigned short* ap = xcat + (m0 + lrow)*K_CAT + lk;
    const unsigned short* bp = wz + (g*128 + ct*32 + lrow)*K_CAT + lk;
    #pragma unroll
    for (int kc = 0; kc < 10; ++kc){
        bf16x8 a0 = *(const bf16x8*)(ap + kc*32);
        bf16x8 a1 = *(const bf16x8*)(ap + 16*K_CAT + kc*32);
        bf16x8 b0 = *(const bf16x8*)(bp + kc*32);
        bf16x8 b1 = *(const bf16x8*)(bp + 16*K_CAT + kc*32);
        acc[0][0] = MFMA16(a0, b0, acc[0][0]);
        acc[0][1] = MFMA16(a0, b1, acc[0][1]);
        acc[1][0] = MFMA16(a1, b0, acc[1][0]);
        acc[1][1] = MFMA16(a1, b1, acc[1][1]);
    }
    const int crow = (lane >> 4) * 4, ccol = lane & 15;
    #pragma unroll
    for (int mi = 0; mi < 2; ++mi)
      #pragma unroll
      for (int ci = 0; ci < 2; ++ci)
        #pragma unroll
        for (int r = 0; r < 4; ++r)
            zbuf[g][mi*16 + crow + r][ci*16 + ccol] = acc[mi][ci][r];
    __syncthreads();

    #pragma unroll
    for (int idx = tid; idx < 1024; idx += 256){
        int r  = idx >> 5, lc = idx & 31;
        int col = ct*32 + lc;
        float zi = zbuf[0][r][lc] + bz[       col];
        float zf = zbuf[1][r][lc] + bz[128  + col];
        float zg = zbuf[2][r][lc] + bz[256  + col];
        float zo = zbuf[3][r][lc] + bz[384  + col];
        float ig = sigm_f(zi);
        float fg = sigm_f(zf);
        float gv = tanh_f(zg);
        float og = sigm_f(zo);
        int gi = (m0 + r)*H_DIM + col;
        float cn = fg * c[gi] + ig * gv;
        float hn = og * tanh_f(cn);
        c[gi] = cn; h[gi] = hn;
        xcat[(m0 + r)*K_CAT + 192 + col] = f2bf(hn);
    }
}

// ---------------- K4: decoder output head (wave per agent) --------------------
__global__ __launch_bounds__(256) void out_head(
    const float* __restrict__ h, const float* __restrict__ W_o,
    const float* __restrict__ b_o, const int* __restrict__ mask,
    float* cur, float* __restrict__ out, int dec_t)
{
    const int a = blockIdx.x * 4 + (threadIdx.x >> 6);
    const int lane = threadIdx.x & 63;
    float h0 = h[a*128 + lane];
    float h1 = h[a*128 + 64 + lane];
    float p[5];
    #pragma unroll
    for (int o = 0; o < 5; ++o)
        p[o] = W_o[o*128 + lane]*h0 + W_o[o*128 + 64 + lane]*h1;
    #pragma unroll
    for (int s = 32; s; s >>= 1)
        #pragma unroll
        for (int o = 0; o < 5; ++o)
            p[o] += __shfl_xor(p[o], s, 64);
    if (lane == 0){
        float mu0 = p[0] + b_o[0];
        float mu1 = p[1] + b_o[1];
        float s0  = __expf(p[2] + b_o[2]) + 1e-6f;
        float s1  = __expf(p[3] + b_o[3]) + 1e-6f;
        float rh  = tanh_f(p[4] + b_o[4]);
        float cx = cur[a*2], cy = cur[a*2+1];
        if (mask[a]){ cx += mu0; cy += mu1; }
        cur[a*2] = cx; cur[a*2+1] = cy;
        out[dec_t*1024 + a*2]             = cx;
        out[dec_t*1024 + a*2 + 1]         = cy;
        out[12288 + dec_t*1024 + a*2]     = s0;
        out[12288 + dec_t*1024 + a*2 + 1] = s1;
        out[24576 + dec_t*512 + a]        = rh;
    }
}

extern "C" void kernel_launch(void* const* d_in, const int* in_sizes, int n_in,
                              void* d_out, int out_size, void* d_ws, size_t ws_size,
                              hipStream_t stream)
{
    const float* obs  = (const float*)d_in[0];
    const unsigned char* mraw = (const unsigned char*)d_in[1];
    const float* W_e  = (const float*)d_in[2];
    const float* b_e  = (const float*)d_in[3];
    const float* W_p  = (const float*)d_in[4];
    const float* b_p  = (const float*)d_in[5];
    const float* W_ih = (const float*)d_in[6];
    const float* W_hh = (const float*)d_in[7];
    const float* b_ih = (const float*)d_in[8];
    const float* b_hh = (const float*)d_in[9];
    const float* W_o  = (const float*)d_in[10];
    const float* b_o  = (const float*)d_in[11];
    float* out = (float*)d_out;

    char* ws = (char*)d_ws;
    unsigned short* wp_bf = (unsigned short*)(ws + WP_OFF);
    unsigned short* wz_bf = (unsigned short*)(ws + WZ_OFF);
    float* bz   = (float*)(ws + BZ_OFF);
    int*   mski = (int*)  (ws + MASK_OFF);
    float* hbuf = (float*)(ws + H_OFF);
    float* cbuf = (float*)(ws + C_OFF);
    float* cur  = (float*)(ws + CUR_OFF);
    unsigned short* xcat = (unsigned short*)(ws + XCAT_OFF);
    unsigned short* grid = (unsigned short*)(ws + GRID_OFF);
    float* part = (float*)(ws + PART_OFF);

    mask_decode<<<1, 512, 0, stream>>>(mraw, mski);
    prep<<<1024, 256, 0, stream>>>(W_p, W_ih, W_hh, b_ih, b_hh,
                                   wp_bf, wz_bf, bz, hbuf, cbuf, xcat);

    for (int t = 0; t < T_OBS + PRED; ++t){
        int mode = (t < T_OBS) ? 0 : ((t == T_OBS) ? 1 : 2);
        scatter_step<<<A_N, 128, 0, stream>>>(obs, W_e, b_e, mski, hbuf, cur,
                                              grid, xcat, mode, t);
        pool_gemm<<<256, 256, 0, stream>>>(grid, wp_bf, part);
        soc_reduce<<<256, 256, 0, stream>>>(part, b_p, mski, xcat);
        lstm64<<<64, 256, 0, stream>>>(xcat, wz_bf, bz, hbuf, cbuf);
        if (t >= T_OBS)
            out_head<<<128, 256, 0, stream>>>(hbuf, W_o, b_o, mski, cur, out,
                                              t - T_OBS);
    }
}